// Round 2
// baseline (1771.392 us; speedup 1.0000x reference)
//
#include <hip/hip_runtime.h>
#include <hip/hip_bf16.h>

typedef __attribute__((ext_vector_type(8))) short short8;
typedef __attribute__((ext_vector_type(16))) float f32x16;

typedef const __attribute__((address_space(1))) unsigned int* gas1_t;
typedef __attribute__((address_space(3))) unsigned int* las3_t;

__device__ __forceinline__ unsigned short f2bf(float x) {
    unsigned int u = __float_as_uint(x);
    u = (u + 0x7fffu + ((u >> 16) & 1u)) >> 16;   // RNE
    return (unsigned short)u;
}

__device__ __forceinline__ int4 pack8(const unsigned short* u) {
    int4 p;
    p.x = (int)((unsigned)u[0] | ((unsigned)u[1] << 16));
    p.y = (int)((unsigned)u[2] | ((unsigned)u[3] << 16));
    p.z = (int)((unsigned)u[4] | ((unsigned)u[5] << 16));
    p.w = (int)((unsigned)u[6] | ((unsigned)u[7] << 16));
    return p;
}

__device__ __forceinline__ void gld_lds16(const void* g, void* l) {
    __builtin_amdgcn_global_load_lds((gas1_t)g, (las3_t)l, 16, 0, 0);
}

// ---------------------------------------------------------------------------
// s[cv][b][c] = 1 + PixelNorm(EqualLinear(latent)); grid 16, block 256
__global__ void style_kernel(const float* __restrict__ latent,
                             const float* __restrict__ elw0, const float* __restrict__ elb0,
                             const float* __restrict__ elw1, const float* __restrict__ elb1,
                             float* __restrict__ s_arr) {
    const int cv = blockIdx.x >> 3;
    const int b  = blockIdx.x & 7;
    const int c  = threadIdx.x;
    const float* elw = cv ? elw1 : elw0;
    const float* elb = cv ? elb1 : elb0;

    __shared__ float lat[512];
    lat[c] = latent[b * 512 + c];
    lat[c + 256] = latent[b * 512 + c + 256];
    __syncthreads();

    float accv = 0.f;
    const float* wrow = elw + (size_t)c * 512;
#pragma unroll 8
    for (int k = 0; k < 512; ++k) accv += lat[k] * wrow[k];
    const float lin = accv * 0.04419417382415922f + elb[c];

    float sq = lin * lin;
#pragma unroll
    for (int off = 32; off >= 1; off >>= 1) sq += __shfl_xor(sq, off);
    __shared__ float wsum[4];
    if ((threadIdx.x & 63) == 0) wsum[threadIdx.x >> 6] = sq;
    __syncthreads();
    const float total = wsum[0] + wsum[1] + wsum[2] + wsum[3];
    const float s = 1.0f + lin * rsqrtf(total * (1.0f / 256.0f) + 1e-8f);
    s_arr[(cv * 8 + b) * 256 + c] = s;
}

// wsq[cv][o][c] = sum_t (w*sc)^2 ; grid 512, block 256
__global__ void wsq_kernel(const float* __restrict__ w0, const float* __restrict__ w1,
                           float* __restrict__ wsq) {
    const int cv = blockIdx.x >> 8;
    const int o  = blockIdx.x & 255;
    const int c  = threadIdx.x;
    const float* w = cv ? w1 : w0;
    const size_t base = ((size_t)o * 256 + c) * 9;
    float ssum = 0.f;
#pragma unroll
    for (int t = 0; t < 9; ++t) { float v = w[base + t]; ssum += v * v; }
    wsq[((size_t)cv * 256 + o) * 256 + c] = ssum * (2.0f / 2304.0f);
}

// d[cv][b][o] = rsqrt(sum_c s^2 * wsq + 1e-5) ; grid 16, block 256
__global__ void demod_kernel(const float* __restrict__ s_arr, const float* __restrict__ wsq,
                             float* __restrict__ d_arr) {
    const int cv = blockIdx.x >> 3;
    const int b  = blockIdx.x & 7;
    const int o  = threadIdx.x;
    __shared__ float ss[256];
    float sv = s_arr[(cv * 8 + b) * 256 + o];
    ss[o] = sv * sv;
    __syncthreads();
    const float* wrow = wsq + ((size_t)cv * 256 + o) * 256;
    float accv = 0.f;
#pragma unroll 8
    for (int c = 0; c < 256; ++c) accv += ss[c] * wrow[c];
    d_arr[(cv * 8 + b) * 256 + o] = rsqrtf(accv + 1e-5f);
}

// wmod[b][cc][t] slab of 8192 elems: (o, c5) stored with chunk XOR-swizzle
// (pre-swizzled on the GLOBAL side so global_load_lds stays linear).
// grid (18432, 2), block 256
__global__ void fold_kernel(const float* __restrict__ w0, const float* __restrict__ w1,
                            const float* __restrict__ s_arr, const float* __restrict__ d_arr,
                            unsigned short* __restrict__ wm0, unsigned short* __restrict__ wm1) {
    const int cv = blockIdx.y;
    const int e  = blockIdx.x * 256 + threadIdx.x;       // 0 .. 4718591
    const float* w = cv ? w1 : w0;
    unsigned short* wm = cv ? wm1 : wm0;
    const int slab = e >> 13;            // 0..575  = ((b*8)+cc)*9 + t
    const int idx  = e & 8191;
    const int b  = slab / 72;
    const int s2 = slab - b * 72;
    const int cc = s2 / 9;
    const int t  = s2 - cc * 9;
    const int o  = idx >> 5;
    const int c5 = idx & 31;
    const int c  = cc * 32 + c5;
    const float val = w[((size_t)o * 256 + c) * 9 + t] * 0.029462782549439483f  // sqrt(2/2304)
                    * s_arr[(cv * 8 + b) * 256 + c] * d_arr[(cv * 8 + b) * 256 + o];
    const int chunk = (c5 >> 3) ^ ((o >> 1) & 3);
    wm[((size_t)slab << 13) + o * 32 + (chunk << 3) + (c5 & 7)] = f2bf(val);
}

// x (fp32 NCHW) -> xq (bf16 NHWC8): [b][g=32][h][w][8ch]; grid 32768, block 256
__global__ void convert_kernel(const float* __restrict__ x, unsigned short* __restrict__ xq) {
    const int blk = blockIdx.x;
    const int hh  = blk & 127;
    const int bg_ = blk >> 7;
    const int g   = bg_ & 31;
    const int b   = bg_ >> 5;
    __shared__ float sx[8][128];
    const int tid = threadIdx.x;
#pragma unroll
    for (int i = 0; i < 4; ++i) {
        const int idx = tid + i * 256;
        const int c8 = idx >> 7, p = idx & 127;
        sx[c8][p] = x[(((size_t)b * 256 + g * 8 + c8) * 128 + hh) * 128 + p];
    }
    __syncthreads();
    if (tid < 128) {
        const int p = tid;
        unsigned short u[8];
#pragma unroll
        for (int j = 0; j < 8; ++j) u[j] = f2bf(sx[j][p]);
        *(int4*)(xq + ((((size_t)b * 32 + g) * 128 + hh) * 128 + p) * 8) = pack8(u);
    }
}

// ---------------------------------------------------------------------------
// Modulated conv, implicit GEMM: M=256 (o), N=128 (one output row), K=2304.
// K-order: cc (8 channel blocks) outer, tap (9) inner -> input reuse in L1/L2.
// 4 waves, wave tile 128x64, mfma_f32_32x32x16_bf16, A via global_load_lds.
// Fused: +bias, leaky*sqrt2, PixelNorm; conv0 writes NHWC8 bf16, conv1 fp32 NCHW.
// IN_MODE: 0 = fp32 NCHW (bounds-checked), 1 = bf16 NHWC8 (bounds-checked)
template<int IN_MODE, bool FINAL_OUT>
__global__ __launch_bounds__(256, 2) void conv_kernel(
    const void* __restrict__ in_v, const unsigned short* __restrict__ wmod,
    const float* __restrict__ bias, void* __restrict__ out_v) {

    __shared__ __align__(16) char ldsA[32768];   // 2 x 16 KB weight slabs
    __shared__ __align__(16) char ldsB[16384];   // 2 x 8 KB input tiles [128px][32ch]

    const int tid  = threadIdx.x;
    const int bh   = (blockIdx.x & 7) * 128 + (blockIdx.x >> 3);  // XCD-contiguous
    const int b    = bh >> 7;
    const int h    = bh & 127;
    const int lane = tid & 63;
    const int wr   = tid >> 6;
    const int wm   = wr & 1;        // M half (128 o's)
    const int wn   = wr >> 1;       // N half (64 px)
    const int l31  = lane & 31;
    const int khg  = lane >> 5;     // k-octet group within frag

    const int px = tid & 127;       // staging pixel
    const int bg = tid >> 7;        // staging chunk pair id (0/1)

    // LDS offsets (XOR chunk swizzle: physical_chunk = logical ^ ((row>>1)&3))
    int aoff[4][2], boff[2][2], bwoff[2];
#pragma unroll
    for (int mb = 0; mb < 4; ++mb)
#pragma unroll
        for (int kh = 0; kh < 2; ++kh) {
            const int o = wm * 128 + mb * 32 + l31;
            aoff[mb][kh] = o * 64 + (((khg + kh * 2) ^ ((o >> 1) & 3)) << 4);
        }
#pragma unroll
    for (int nb = 0; nb < 2; ++nb)
#pragma unroll
        for (int kh = 0; kh < 2; ++kh) {
            const int p = wn * 64 + nb * 32 + l31;
            boff[nb][kh] = p * 64 + (((khg + kh * 2) ^ ((p >> 1) & 3)) << 4);
        }
#pragma unroll
    for (int gg = 0; gg < 2; ++gg)
        bwoff[gg] = px * 64 + (((bg * 2 + gg) ^ ((px >> 1) & 3)) << 4);

    const unsigned short* wmb = wmod + (size_t)b * 589824;
    const unsigned short* inq = (const unsigned short*)in_v
                              + ((size_t)b * 32 + bg * 2) * 131072 + (size_t)px * 8;
    const float* inf = (const float*)in_v + ((size_t)b * 256 + bg * 16) * 16384 + px;

    f32x16 acc[4][2];
#pragma unroll
    for (int mb = 0; mb < 4; ++mb)
#pragma unroll
        for (int nb = 0; nb < 2; ++nb)
#pragma unroll
            for (int r = 0; r < 16; ++r) acc[mb][nb][r] = 0.f;

    auto loadB = [&](int ccv, int tv, int4& v0, int4& v1) {
        const int dyv = tv / 3, dxv = tv - (tv / 3) * 3;    // compile-time folds
        const int row = h + dyv - 1;
        const bool ok = ((unsigned)row < 128u) && ((unsigned)(px + dxv - 1) < 128u);
        if (IN_MODE == 1) {
            const unsigned short* p = inq + (size_t)(ccv * 4) * 131072
                                    + (size_t)row * 1024 + (dxv - 1) * 8;
            const int4 z = {0, 0, 0, 0};
            v0 = ok ? *(const int4*)p : z;
            v1 = ok ? *(const int4*)(p + 131072) : z;
        } else {
            unsigned short us[16];
            const float* p = inf + (size_t)(ccv * 32) * 16384 + (size_t)row * 128 + (dxv - 1);
#pragma unroll
            for (int j = 0; j < 16; ++j) us[j] = f2bf(ok ? p[(size_t)j * 16384] : 0.f);
            v0 = pack8(us);
            v1 = pack8(us + 8);
        }
    };

    auto issueA = [&](const char* gsrc, int nxt) {
        char* dst = ldsA + nxt * 16384 + wr * 4096;
        const char* s = gsrc + wr * 4096 + lane * 16;
        gld_lds16(s,        dst);
        gld_lds16(s + 1024, dst + 1024);
        gld_lds16(s + 2048, dst + 2048);
        gld_lds16(s + 3072, dst + 3072);
    };

    // prologue: stage step 0 into buffer 0
    {
        int4 v0, v1;
        loadB(0, 0, v0, v1);
        issueA((const char*)wmb, 0);
        *(int4*)(ldsB + bwoff[0]) = v0;
        *(int4*)(ldsB + bwoff[1]) = v1;
    }
    __syncthreads();

    const char* gA = (const char*)wmb + 16384;
#pragma unroll 1
    for (int cc = 0; cc < 8; ++cc) {
#pragma unroll
        for (int t = 0; t < 9; ++t) {
            const int cur = (cc + t) & 1;
            const int nxt = cur ^ 1;
            const bool notLast = !(cc == 7 && t == 8);
            int4 v0, v1;
            if (notLast) {
                const int tn  = (t == 8) ? 0 : (t + 1);
                const int ccn = (t == 8) ? (cc + 1) : cc;
                loadB(ccn, tn, v0, v1);
                issueA(gA, nxt);
                gA += 16384;
            }
            const char* Ac = ldsA + cur * 16384;
            const char* Bc = ldsB + cur * 8192;
            short8 af[4][2], bf[2][2];
#pragma unroll
            for (int mb = 0; mb < 4; ++mb)
#pragma unroll
                for (int kh = 0; kh < 2; ++kh) af[mb][kh] = *(const short8*)(Ac + aoff[mb][kh]);
#pragma unroll
            for (int nb = 0; nb < 2; ++nb)
#pragma unroll
                for (int kh = 0; kh < 2; ++kh) bf[nb][kh] = *(const short8*)(Bc + boff[nb][kh]);
#pragma unroll
            for (int kh = 0; kh < 2; ++kh)
#pragma unroll
                for (int mb = 0; mb < 4; ++mb)
#pragma unroll
                    for (int nb = 0; nb < 2; ++nb)
                        acc[mb][nb] = __builtin_amdgcn_mfma_f32_32x32x16_bf16(
                            af[mb][kh], bf[nb][kh], acc[mb][nb], 0, 0, 0);
            if (notLast) {
                *(int4*)(ldsB + nxt * 8192 + bwoff[0]) = v0;
                *(int4*)(ldsB + nxt * 8192 + bwoff[1]) = v1;
            }
            __syncthreads();
        }
    }

    // ---------------- epilogue: bias + leaky*sqrt2 + PixelNorm ----------------
    float* sb = (float*)ldsB;
    sb[tid] = bias[tid];
    __syncthreads();

    float psum[2] = {0.f, 0.f};
    const float actGain = 1.4142135623730951f;
#pragma unroll
    for (int mb = 0; mb < 4; ++mb)
#pragma unroll
        for (int rg = 0; rg < 16; ++rg) {
            const int row = (rg & 3) + 8 * (rg >> 2) + 4 * khg;
            const float bo = sb[wm * 128 + mb * 32 + row];
#pragma unroll
            for (int nb = 0; nb < 2; ++nb) {
                float v = acc[mb][nb][rg] + bo;
                v = (v > 0.f ? v : 0.2f * v) * actGain;
                acc[mb][nb][rg] = v;
                psum[nb] += v * v;
            }
        }
    psum[0] += __shfl_xor(psum[0], 32);
    psum[1] += __shfl_xor(psum[1], 32);
    float* red = (float*)ldsA;
    if (lane < 32) {
        red[(wn * 2 + wm) * 64 + l31]      = psum[0];
        red[(wn * 2 + wm) * 64 + 32 + l31] = psum[1];
    }
    __syncthreads();
    float rs[2];
#pragma unroll
    for (int nb = 0; nb < 2; ++nb) {
        const float ssum = red[(wn * 2) * 64 + nb * 32 + l31]
                         + red[(wn * 2 + 1) * 64 + nb * 32 + l31];
        rs[nb] = rsqrtf(ssum * (1.0f / 256.0f) + 1e-8f);
    }

    if (FINAL_OUT) {
        float* outF = (float*)out_v;
#pragma unroll
        for (int mb = 0; mb < 4; ++mb)
#pragma unroll
            for (int rg = 0; rg < 16; ++rg) {
                const int row = (rg & 3) + 8 * (rg >> 2) + 4 * khg;
                const int o = wm * 128 + mb * 32 + row;
                const size_t rb = (((size_t)b * 256 + o) * 128 + h) * 128;
#pragma unroll
                for (int nb = 0; nb < 2; ++nb)
                    outF[rb + wn * 64 + nb * 32 + l31] = acc[mb][nb][rg] * rs[nb];
            }
    } else {
        // transpose 128o x 64px (per wave) -> NHWC8 bf16 via per-wave LDS region
        unsigned short* outB = (unsigned short*)out_v;
        char* wreg = ldsA + wr * 4096;    // [64 px][32 o] bf16, chunk-swizzled
        __syncthreads();                  // red reads done before overwriting ldsA
#pragma unroll 1
        for (int mb = 0; mb < 4; ++mb) {
#pragma unroll
            for (int rg = 0; rg < 16; ++rg) {
                const int row = (rg & 3) + 8 * (rg >> 2) + 4 * khg;   // 0..31
#pragma unroll
                for (int nb = 0; nb < 2; ++nb) {
                    const int pxl = nb * 32 + l31;
                    *(unsigned short*)(wreg + pxl * 64 + (((row >> 3) ^ (pxl & 3)) << 4)
                                       + (row & 7) * 2) = f2bf(acc[mb][nb][rg] * rs[nb]);
                }
            }
            asm volatile("s_waitcnt lgkmcnt(0)" ::: "memory");
#pragma unroll
            for (int oc = 0; oc < 4; ++oc) {
                const int4 v = *(const int4*)(wreg + lane * 64 + ((oc ^ (lane & 3)) << 4));
                const int g = wm * 16 + mb * 4 + oc;
                *(int4*)(outB + ((((size_t)b * 32 + g) * 128 + h) * 128 + wn * 64 + lane) * 8) = v;
            }
            asm volatile("s_waitcnt lgkmcnt(0) vmcnt(0)" ::: "memory");
        }
    }
}

// ---------------------------------------------------------------------------
extern "C" void kernel_launch(void* const* d_in, const int* in_sizes, int n_in,
                              void* d_out, int out_size, void* d_ws, size_t ws_size,
                              hipStream_t stream) {
    (void)in_sizes; (void)n_in; (void)out_size;
    const float* x      = (const float*)d_in[0];
    const float* latent = (const float*)d_in[1];
    const float* w0     = (const float*)d_in[2];
    const float* b0     = (const float*)d_in[3];
    const float* el0w   = (const float*)d_in[4];
    const float* el0b   = (const float*)d_in[5];
    const float* w1     = (const float*)d_in[6];
    const float* b1     = (const float*)d_in[7];
    const float* el1w   = (const float*)d_in[8];
    const float* el1b   = (const float*)d_in[9];

    char* ws = (char*)d_ws;
    float* s_arr = (float*)ws;                                   // 16 KB
    float* d_arr = (float*)(ws + 16384);                         // 16 KB
    float* wsq   = (float*)(ws + 32768);                         // 512 KB
    unsigned short* wm0 = (unsigned short*)(ws + 557056);        // 9.4 MB
    unsigned short* wm1 = (unsigned short*)(ws + 9994240);       // 9.4 MB
    const bool full = ws_size >= (size_t)153649152;
    unsigned short* xq  = (unsigned short*)(ws + 19431424);                     // 67 MB (full only)
    unsigned short* tmp = (unsigned short*)(ws + (full ? 86540288 : 19431424)); // 67 MB

    style_kernel<<<16, 256, 0, stream>>>(latent, el0w, el0b, el1w, el1b, s_arr);
    wsq_kernel<<<512, 256, 0, stream>>>(w0, w1, wsq);
    demod_kernel<<<16, 256, 0, stream>>>(s_arr, wsq, d_arr);
    fold_kernel<<<dim3(18432, 2), 256, 0, stream>>>(w0, w1, s_arr, d_arr, wm0, wm1);

    if (full) {
        convert_kernel<<<32768, 256, 0, stream>>>(x, xq);
        conv_kernel<1, false><<<1024, 256, 0, stream>>>(xq, wm0, b0, tmp);
    } else {
        conv_kernel<0, false><<<1024, 256, 0, stream>>>(x, wm0, b0, tmp);
    }
    conv_kernel<1, true><<<1024, 256, 0, stream>>>(tmp, wm1, b1, d_out);
}

// Round 3
// 414.513 us; speedup vs baseline: 4.2734x; 4.2734x over previous
//
#include <hip/hip_runtime.h>
#include <hip/hip_bf16.h>

typedef __attribute__((ext_vector_type(8))) short short8;
typedef __attribute__((ext_vector_type(16))) float f32x16;

typedef const __attribute__((address_space(1))) unsigned int* gas1_t;
typedef __attribute__((address_space(3))) unsigned int* las3_t;

__device__ __forceinline__ unsigned short f2bf(float x) {
    unsigned int u = __float_as_uint(x);
    u = (u + 0x7fffu + ((u >> 16) & 1u)) >> 16;   // RNE
    return (unsigned short)u;
}

__device__ __forceinline__ int4 pack8(const unsigned short* u) {
    int4 p;
    p.x = (int)((unsigned)u[0] | ((unsigned)u[1] << 16));
    p.y = (int)((unsigned)u[2] | ((unsigned)u[3] << 16));
    p.z = (int)((unsigned)u[4] | ((unsigned)u[5] << 16));
    p.w = (int)((unsigned)u[6] | ((unsigned)u[7] << 16));
    return p;
}

__device__ __forceinline__ void gld_lds16(const void* g, void* l) {
    __builtin_amdgcn_global_load_lds((gas1_t)g, (las3_t)l, 16, 0, 0);
}

// ---------------------------------------------------------------------------
// s[cv][b][c] = 1 + PixelNorm(EqualLinear(latent)); grid 16, block 256
__global__ void style_kernel(const float* __restrict__ latent,
                             const float* __restrict__ elw0, const float* __restrict__ elb0,
                             const float* __restrict__ elw1, const float* __restrict__ elb1,
                             float* __restrict__ s_arr) {
    const int cv = blockIdx.x >> 3;
    const int b  = blockIdx.x & 7;
    const int c  = threadIdx.x;
    const float* elw = cv ? elw1 : elw0;
    const float* elb = cv ? elb1 : elb0;

    __shared__ float lat[512];
    lat[c] = latent[b * 512 + c];
    lat[c + 256] = latent[b * 512 + c + 256];
    __syncthreads();

    float accv = 0.f;
    const float* wrow = elw + (size_t)c * 512;
#pragma unroll 8
    for (int k = 0; k < 512; ++k) accv += lat[k] * wrow[k];
    const float lin = accv * 0.04419417382415922f + elb[c];

    float sq = lin * lin;
#pragma unroll
    for (int off = 32; off >= 1; off >>= 1) sq += __shfl_xor(sq, off);
    __shared__ float wsum[4];
    if ((threadIdx.x & 63) == 0) wsum[threadIdx.x >> 6] = sq;
    __syncthreads();
    const float total = wsum[0] + wsum[1] + wsum[2] + wsum[3];
    const float s = 1.0f + lin * rsqrtf(total * (1.0f / 256.0f) + 1e-8f);
    s_arr[(cv * 8 + b) * 256 + c] = s;
}

// wsq[cv][o][c] = sum_t (w*sc)^2 ; grid 512, block 256
__global__ void wsq_kernel(const float* __restrict__ w0, const float* __restrict__ w1,
                           float* __restrict__ wsq) {
    const int cv = blockIdx.x >> 8;
    const int o  = blockIdx.x & 255;
    const int c  = threadIdx.x;
    const float* w = cv ? w1 : w0;
    const size_t base = ((size_t)o * 256 + c) * 9;
    float ssum = 0.f;
#pragma unroll
    for (int t = 0; t < 9; ++t) { float v = w[base + t]; ssum += v * v; }
    wsq[((size_t)cv * 256 + o) * 256 + c] = ssum * (2.0f / 2304.0f);
}

// d[cv][b][o] = rsqrt(sum_c s^2 * wsq + 1e-5) ; grid 16, block 256
__global__ void demod_kernel(const float* __restrict__ s_arr, const float* __restrict__ wsq,
                             float* __restrict__ d_arr) {
    const int cv = blockIdx.x >> 3;
    const int b  = blockIdx.x & 7;
    const int o  = threadIdx.x;
    __shared__ float ss[256];
    float sv = s_arr[(cv * 8 + b) * 256 + o];
    ss[o] = sv * sv;
    __syncthreads();
    const float* wrow = wsq + ((size_t)cv * 256 + o) * 256;
    float accv = 0.f;
#pragma unroll 8
    for (int c = 0; c < 256; ++c) accv += ss[c] * wrow[c];
    d_arr[(cv * 8 + b) * 256 + o] = rsqrtf(accv + 1e-5f);
}

// wmod[b][cc][t] slab of 8192 elems: (o, c5) stored with chunk XOR-swizzle
// (pre-swizzled on the GLOBAL side so global_load_lds stays linear).
// grid (18432, 2), block 256
__global__ void fold_kernel(const float* __restrict__ w0, const float* __restrict__ w1,
                            const float* __restrict__ s_arr, const float* __restrict__ d_arr,
                            unsigned short* __restrict__ wm0, unsigned short* __restrict__ wm1) {
    const int cv = blockIdx.y;
    const int e  = blockIdx.x * 256 + threadIdx.x;       // 0 .. 4718591
    const float* w = cv ? w1 : w0;
    unsigned short* wm = cv ? wm1 : wm0;
    const int slab = e >> 13;            // 0..575  = ((b*8)+cc)*9 + t
    const int idx  = e & 8191;
    const int b  = slab / 72;
    const int s2 = slab - b * 72;
    const int cc = s2 / 9;
    const int t  = s2 - cc * 9;
    const int o  = idx >> 5;
    const int c5 = idx & 31;
    const int c  = cc * 32 + c5;
    const float val = w[((size_t)o * 256 + c) * 9 + t] * 0.029462782549439483f  // sqrt(2/2304)
                    * s_arr[(cv * 8 + b) * 256 + c] * d_arr[(cv * 8 + b) * 256 + o];
    const int chunk = (c5 >> 3) ^ ((o >> 1) & 3);
    wm[((size_t)slab << 13) + o * 32 + (chunk << 3) + (c5 & 7)] = f2bf(val);
}

// x (fp32 NCHW) -> xq (bf16 NHWC8): [b][g=32][h][w][8ch]; grid 32768, block 256
__global__ void convert_kernel(const float* __restrict__ x, unsigned short* __restrict__ xq) {
    const int blk = blockIdx.x;
    const int hh  = blk & 127;
    const int bg_ = blk >> 7;
    const int g   = bg_ & 31;
    const int b   = bg_ >> 5;
    __shared__ float sx[8][128];
    const int tid = threadIdx.x;
#pragma unroll
    for (int i = 0; i < 4; ++i) {
        const int idx = tid + i * 256;
        const int c8 = idx >> 7, p = idx & 127;
        sx[c8][p] = x[(((size_t)b * 256 + g * 8 + c8) * 128 + hh) * 128 + p];
    }
    __syncthreads();
    if (tid < 128) {
        const int p = tid;
        unsigned short u[8];
#pragma unroll
        for (int j = 0; j < 8; ++j) u[j] = f2bf(sx[j][p]);
        *(int4*)(xq + ((((size_t)b * 32 + g) * 128 + hh) * 128 + p) * 8) = pack8(u);
    }
}

// ---------------------------------------------------------------------------
// Modulated conv, implicit GEMM: M=256 (o), N=128 (one output row), K=2304.
// K-order: cc (8 channel blocks) outer, tap (9) inner -> input reuse in L1/L2.
// 4 waves, wave tile 128x64, mfma_f32_32x32x16_bf16, A via global_load_lds.
// Fused: +bias, leaky*sqrt2, PixelNorm; conv0 writes NHWC8 bf16, conv1 fp32 NCHW.
// IN_MODE: 0 = fp32 NCHW (bounds-checked), 1 = bf16 NHWC8 (bounds-checked)
template<int IN_MODE, bool FINAL_OUT>
__global__ __launch_bounds__(256, 2) void conv_kernel(
    const void* __restrict__ in_v, const unsigned short* __restrict__ wmod,
    const float* __restrict__ bias, void* __restrict__ out_v) {

    __shared__ __align__(16) char ldsA[32768];   // 2 x 16 KB weight slabs
    __shared__ __align__(16) char ldsB[16384];   // 2 x 8 KB input tiles [128px][32ch]

    const int tid  = threadIdx.x;
    const int bh   = (blockIdx.x & 7) * 128 + (blockIdx.x >> 3);  // XCD-contiguous
    const int b    = bh >> 7;
    const int h    = bh & 127;
    const int lane = tid & 63;
    const int wr   = tid >> 6;
    const int wm   = wr & 1;        // M half (128 o's)
    const int wn   = wr >> 1;       // N half (64 px)
    const int l31  = lane & 31;
    const int khg  = lane >> 5;     // k-octet group within frag

    const int px = tid & 127;       // staging pixel
    const int bg = tid >> 7;        // staging chunk pair id (0/1)

    // LDS offsets (XOR chunk swizzle: physical_chunk = logical ^ ((row>>1)&3))
    int aoff[4][2], boff[2][2], bwoff[2];
#pragma unroll
    for (int mb = 0; mb < 4; ++mb)
#pragma unroll
        for (int kh = 0; kh < 2; ++kh) {
            const int o = wm * 128 + mb * 32 + l31;
            aoff[mb][kh] = o * 64 + (((khg + kh * 2) ^ ((o >> 1) & 3)) << 4);
        }
#pragma unroll
    for (int nb = 0; nb < 2; ++nb)
#pragma unroll
        for (int kh = 0; kh < 2; ++kh) {
            const int p = wn * 64 + nb * 32 + l31;
            boff[nb][kh] = p * 64 + (((khg + kh * 2) ^ ((p >> 1) & 3)) << 4);
        }
#pragma unroll
    for (int gg = 0; gg < 2; ++gg)
        bwoff[gg] = px * 64 + (((bg * 2 + gg) ^ ((px >> 1) & 3)) << 4);

    const unsigned short* wmb = wmod + (size_t)b * 589824;
    const unsigned short* inq = (const unsigned short*)in_v
                              + ((size_t)b * 32 + bg * 2) * 131072 + (size_t)px * 8;
    const float* inf = (const float*)in_v + ((size_t)b * 256 + bg * 16) * 16384 + px;

    f32x16 acc[4][2];
#pragma unroll
    for (int mb = 0; mb < 4; ++mb)
#pragma unroll
        for (int nb = 0; nb < 2; ++nb)
#pragma unroll
            for (int r = 0; r < 16; ++r) acc[mb][nb][r] = 0.f;

    auto loadB = [&](int ccv, int tv, int4& v0, int4& v1) {
        const int dyv = tv / 3, dxv = tv - (tv / 3) * 3;    // compile-time folds
        const int row = h + dyv - 1;
        const bool ok = ((unsigned)row < 128u) && ((unsigned)(px + dxv - 1) < 128u);
        if (IN_MODE == 1) {
            const unsigned short* p = inq + (size_t)(ccv * 4) * 131072
                                    + (size_t)row * 1024 + (dxv - 1) * 8;
            const int4 z = {0, 0, 0, 0};
            v0 = ok ? *(const int4*)p : z;
            v1 = ok ? *(const int4*)(p + 131072) : z;
        } else {
            unsigned short us[16];
            const float* p = inf + (size_t)(ccv * 32) * 16384 + (size_t)row * 128 + (dxv - 1);
#pragma unroll
            for (int j = 0; j < 16; ++j) us[j] = f2bf(ok ? p[(size_t)j * 16384] : 0.f);
            v0 = pack8(us);
            v1 = pack8(us + 8);
        }
    };

    auto issueA = [&](const char* gsrc, int nxt) {
        char* dst = ldsA + nxt * 16384 + wr * 4096;
        const char* s = gsrc + wr * 4096 + lane * 16;
        gld_lds16(s,        dst);
        gld_lds16(s + 1024, dst + 1024);
        gld_lds16(s + 2048, dst + 2048);
        gld_lds16(s + 3072, dst + 3072);
    };

    // prologue: stage step 0 into buffer 0
    {
        int4 v0, v1;
        loadB(0, 0, v0, v1);
        issueA((const char*)wmb, 0);
        *(int4*)(ldsB + bwoff[0]) = v0;
        *(int4*)(ldsB + bwoff[1]) = v1;
    }
    __syncthreads();

    const char* gA = (const char*)wmb + 16384;
#pragma unroll 1
    for (int cc = 0; cc < 8; ++cc) {
#pragma unroll
        for (int t = 0; t < 9; ++t) {
            const int cur = (cc + t) & 1;
            const int nxt = cur ^ 1;
            const bool notLast = !(cc == 7 && t == 8);
            int4 v0, v1;
            if (notLast) {
                const int tn  = (t == 8) ? 0 : (t + 1);
                const int ccn = (t == 8) ? (cc + 1) : cc;
                loadB(ccn, tn, v0, v1);
                issueA(gA, nxt);
                gA += 16384;
            }
            const char* Ac = ldsA + cur * 16384;
            const char* Bc = ldsB + cur * 8192;
            short8 af[4][2], bf[2][2];
#pragma unroll
            for (int mb = 0; mb < 4; ++mb)
#pragma unroll
                for (int kh = 0; kh < 2; ++kh) af[mb][kh] = *(const short8*)(Ac + aoff[mb][kh]);
#pragma unroll
            for (int nb = 0; nb < 2; ++nb)
#pragma unroll
                for (int kh = 0; kh < 2; ++kh) bf[nb][kh] = *(const short8*)(Bc + boff[nb][kh]);
#pragma unroll
            for (int kh = 0; kh < 2; ++kh)
#pragma unroll
                for (int mb = 0; mb < 4; ++mb)
#pragma unroll
                    for (int nb = 0; nb < 2; ++nb)
                        acc[mb][nb] = __builtin_amdgcn_mfma_f32_32x32x16_bf16(
                            af[mb][kh], bf[nb][kh], acc[mb][nb], 0, 0, 0);
            if (notLast) {
                *(int4*)(ldsB + nxt * 8192 + bwoff[0]) = v0;
                *(int4*)(ldsB + nxt * 8192 + bwoff[1]) = v1;
            }
            __syncthreads();
        }
    }

    // ---------------- epilogue: bias + leaky*sqrt2 + PixelNorm ----------------
    float* sb = (float*)ldsB;
    sb[tid] = bias[tid];
    __syncthreads();

    float psum[2] = {0.f, 0.f};
    const float actGain = 1.4142135623730951f;
#pragma unroll
    for (int mb = 0; mb < 4; ++mb)
#pragma unroll
        for (int rg = 0; rg < 16; ++rg) {
            const int row = (rg & 3) + 8 * (rg >> 2) + 4 * khg;
            const float bo = sb[wm * 128 + mb * 32 + row];
#pragma unroll
            for (int nb = 0; nb < 2; ++nb) {
                float v = acc[mb][nb][rg] + bo;
                v = (v > 0.f ? v : 0.2f * v) * actGain;
                acc[mb][nb][rg] = v;
                psum[nb] += v * v;
            }
        }
    psum[0] += __shfl_xor(psum[0], 32);
    psum[1] += __shfl_xor(psum[1], 32);
    float* red = (float*)ldsA;
    if (lane < 32) {
        red[(wn * 2 + wm) * 64 + l31]      = psum[0];
        red[(wn * 2 + wm) * 64 + 32 + l31] = psum[1];
    }
    __syncthreads();
    float rs[2];
#pragma unroll
    for (int nb = 0; nb < 2; ++nb) {
        const float ssum = red[(wn * 2) * 64 + nb * 32 + l31]
                         + red[(wn * 2 + 1) * 64 + nb * 32 + l31];
        rs[nb] = rsqrtf(ssum * (1.0f / 256.0f) + 1e-8f);
    }

    if (FINAL_OUT) {
        float* outF = (float*)out_v;
#pragma unroll
        for (int mb = 0; mb < 4; ++mb)
#pragma unroll
            for (int rg = 0; rg < 16; ++rg) {
                const int row = (rg & 3) + 8 * (rg >> 2) + 4 * khg;
                const int o = wm * 128 + mb * 32 + row;
                const size_t rb = (((size_t)b * 256 + o) * 128 + h) * 128;
#pragma unroll
                for (int nb = 0; nb < 2; ++nb)
                    outF[rb + wn * 64 + nb * 32 + l31] = acc[mb][nb][rg] * rs[nb];
            }
    } else {
        // transpose 128o x 64px (per wave) -> NHWC8 bf16 via per-wave LDS region.
        // FULLY UNROLLED (rule #20: runtime mb would force acc into scratch).
        unsigned short* outB = (unsigned short*)out_v;
        char* wreg = ldsA + wr * 4096;    // [64 px][32 o] bf16, chunk-swizzled
        __syncthreads();                  // red reads done before overwriting ldsA
#pragma unroll
        for (int mb = 0; mb < 4; ++mb) {
#pragma unroll
            for (int rg = 0; rg < 16; rg += 2) {
                const int row = (rg & 3) + 8 * (rg >> 2) + 4 * khg;   // even, 0..31
#pragma unroll
                for (int nb = 0; nb < 2; ++nb) {
                    const int pxl = nb * 32 + l31;
                    const unsigned lo = f2bf(acc[mb][nb][rg]     * rs[nb]);
                    const unsigned hi = f2bf(acc[mb][nb][rg + 1] * rs[nb]);
                    *(unsigned int*)(wreg + pxl * 64 + (((row >> 3) ^ (pxl & 3)) << 4)
                                     + (row & 7) * 2) = lo | (hi << 16);
                }
            }
            asm volatile("s_waitcnt lgkmcnt(0)" ::: "memory");
#pragma unroll
            for (int oc = 0; oc < 4; ++oc) {
                const int4 v = *(const int4*)(wreg + lane * 64 + ((oc ^ (lane & 3)) << 4));
                const int g = wm * 16 + mb * 4 + oc;
                *(int4*)(outB + ((((size_t)b * 32 + g) * 128 + h) * 128 + wn * 64 + lane) * 8) = v;
            }
            asm volatile("s_waitcnt lgkmcnt(0)" ::: "memory");
        }
    }
}

// ---------------------------------------------------------------------------
extern "C" void kernel_launch(void* const* d_in, const int* in_sizes, int n_in,
                              void* d_out, int out_size, void* d_ws, size_t ws_size,
                              hipStream_t stream) {
    (void)in_sizes; (void)n_in; (void)out_size;
    const float* x      = (const float*)d_in[0];
    const float* latent = (const float*)d_in[1];
    const float* w0     = (const float*)d_in[2];
    const float* b0     = (const float*)d_in[3];
    const float* el0w   = (const float*)d_in[4];
    const float* el0b   = (const float*)d_in[5];
    const float* w1     = (const float*)d_in[6];
    const float* b1     = (const float*)d_in[7];
    const float* el1w   = (const float*)d_in[8];
    const float* el1b   = (const float*)d_in[9];

    char* ws = (char*)d_ws;
    float* s_arr = (float*)ws;                                   // 16 KB
    float* d_arr = (float*)(ws + 16384);                         // 16 KB
    float* wsq   = (float*)(ws + 32768);                         // 512 KB
    unsigned short* wm0 = (unsigned short*)(ws + 557056);        // 9.4 MB
    unsigned short* wm1 = (unsigned short*)(ws + 9994240);       // 9.4 MB
    const bool full = ws_size >= (size_t)153649152;
    unsigned short* xq  = (unsigned short*)(ws + 19431424);                     // 67 MB (full only)
    unsigned short* tmp = (unsigned short*)(ws + (full ? 86540288 : 19431424)); // 67 MB

    style_kernel<<<16, 256, 0, stream>>>(latent, el0w, el0b, el1w, el1b, s_arr);
    wsq_kernel<<<512, 256, 0, stream>>>(w0, w1, wsq);
    demod_kernel<<<16, 256, 0, stream>>>(s_arr, wsq, d_arr);
    fold_kernel<<<dim3(18432, 2), 256, 0, stream>>>(w0, w1, s_arr, d_arr, wm0, wm1);

    if (full) {
        convert_kernel<<<32768, 256, 0, stream>>>(x, xq);
        conv_kernel<1, false><<<1024, 256, 0, stream>>>(xq, wm0, b0, tmp);
    } else {
        conv_kernel<0, false><<<1024, 256, 0, stream>>>(x, wm0, b0, tmp);
    }
    conv_kernel<1, true><<<1024, 256, 0, stream>>>(tmp, wm1, b1, d_out);
}

// Round 4
// 398.487 us; speedup vs baseline: 4.4453x; 1.0402x over previous
//
#include <hip/hip_runtime.h>
#include <hip/hip_bf16.h>

typedef __attribute__((ext_vector_type(8))) short short8;
typedef __attribute__((ext_vector_type(16))) float f32x16;

typedef const __attribute__((address_space(1))) unsigned int* gas1_t;
typedef __attribute__((address_space(3))) unsigned int* las3_t;

__device__ __forceinline__ unsigned short f2bf(float x) {
    unsigned int u = __float_as_uint(x);
    u = (u + 0x7fffu + ((u >> 16) & 1u)) >> 16;   // RNE
    return (unsigned short)u;
}

__device__ __forceinline__ int4 pack8(const unsigned short* u) {
    int4 p;
    p.x = (int)((unsigned)u[0] | ((unsigned)u[1] << 16));
    p.y = (int)((unsigned)u[2] | ((unsigned)u[3] << 16));
    p.z = (int)((unsigned)u[4] | ((unsigned)u[5] << 16));
    p.w = (int)((unsigned)u[6] | ((unsigned)u[7] << 16));
    return p;
}

__device__ __forceinline__ void gld_lds16(const void* g, void* l) {
    __builtin_amdgcn_global_load_lds((gas1_t)g, (las3_t)l, 16, 0, 0);
}

// ---------------------------------------------------------------------------
// s[cv][b][c] = 1 + PixelNorm(EqualLinear(latent)); grid 16, block 256
__global__ void style_kernel(const float* __restrict__ latent,
                             const float* __restrict__ elw0, const float* __restrict__ elb0,
                             const float* __restrict__ elw1, const float* __restrict__ elb1,
                             float* __restrict__ s_arr) {
    const int cv = blockIdx.x >> 3;
    const int b  = blockIdx.x & 7;
    const int c  = threadIdx.x;
    const float* elw = cv ? elw1 : elw0;
    const float* elb = cv ? elb1 : elb0;

    __shared__ float lat[512];
    lat[c] = latent[b * 512 + c];
    lat[c + 256] = latent[b * 512 + c + 256];
    __syncthreads();

    float accv = 0.f;
    const float* wrow = elw + (size_t)c * 512;
#pragma unroll 8
    for (int k = 0; k < 512; ++k) accv += lat[k] * wrow[k];
    const float lin = accv * 0.04419417382415922f + elb[c];

    float sq = lin * lin;
#pragma unroll
    for (int off = 32; off >= 1; off >>= 1) sq += __shfl_xor(sq, off);
    __shared__ float wsum[4];
    if ((threadIdx.x & 63) == 0) wsum[threadIdx.x >> 6] = sq;
    __syncthreads();
    const float total = wsum[0] + wsum[1] + wsum[2] + wsum[3];
    const float s = 1.0f + lin * rsqrtf(total * (1.0f / 256.0f) + 1e-8f);
    s_arr[(cv * 8 + b) * 256 + c] = s;
}

// wsq[cv][o][c] = sum_t (w*sc)^2 ; grid 512, block 256
__global__ void wsq_kernel(const float* __restrict__ w0, const float* __restrict__ w1,
                           float* __restrict__ wsq) {
    const int cv = blockIdx.x >> 8;
    const int o  = blockIdx.x & 255;
    const int c  = threadIdx.x;
    const float* w = cv ? w1 : w0;
    const size_t base = ((size_t)o * 256 + c) * 9;
    float ssum = 0.f;
#pragma unroll
    for (int t = 0; t < 9; ++t) { float v = w[base + t]; ssum += v * v; }
    wsq[((size_t)cv * 256 + o) * 256 + c] = ssum * (2.0f / 2304.0f);
}

// d[cv][b][o] = rsqrt(sum_c s^2 * wsq + 1e-5) ; grid 16, block 256
__global__ void demod_kernel(const float* __restrict__ s_arr, const float* __restrict__ wsq,
                             float* __restrict__ d_arr) {
    const int cv = blockIdx.x >> 3;
    const int b  = blockIdx.x & 7;
    const int o  = threadIdx.x;
    __shared__ float ss[256];
    float sv = s_arr[(cv * 8 + b) * 256 + o];
    ss[o] = sv * sv;
    __syncthreads();
    const float* wrow = wsq + ((size_t)cv * 256 + o) * 256;
    float accv = 0.f;
#pragma unroll 8
    for (int c = 0; c < 256; ++c) accv += ss[c] * wrow[c];
    d_arr[(cv * 8 + b) * 256 + o] = rsqrtf(accv + 1e-5f);
}

// wmod[b][cc][t] slab of 8192 elems: (o, c5) stored with chunk XOR-swizzle
// (pre-swizzled on the GLOBAL side so global_load_lds stays linear).
// grid (18432, 2), block 256
__global__ void fold_kernel(const float* __restrict__ w0, const float* __restrict__ w1,
                            const float* __restrict__ s_arr, const float* __restrict__ d_arr,
                            unsigned short* __restrict__ wm0, unsigned short* __restrict__ wm1) {
    const int cv = blockIdx.y;
    const int e  = blockIdx.x * 256 + threadIdx.x;       // 0 .. 4718591
    const float* w = cv ? w1 : w0;
    unsigned short* wm = cv ? wm1 : wm0;
    const int slab = e >> 13;            // 0..575  = ((b*8)+cc)*9 + t
    const int idx  = e & 8191;
    const int b  = slab / 72;
    const int s2 = slab - b * 72;
    const int cc = s2 / 9;
    const int t  = s2 - cc * 9;
    const int o  = idx >> 5;
    const int c5 = idx & 31;
    const int c  = cc * 32 + c5;
    const float val = w[((size_t)o * 256 + c) * 9 + t] * 0.029462782549439483f  // sqrt(2/2304)
                    * s_arr[(cv * 8 + b) * 256 + c] * d_arr[(cv * 8 + b) * 256 + o];
    const int chunk = (c5 >> 3) ^ ((o >> 1) & 3);
    wm[((size_t)slab << 13) + o * 32 + (chunk << 3) + (c5 & 7)] = f2bf(val);
}

// x (fp32 NCHW) -> xq (bf16 NHWC8): [b][g=32][h][w][8ch]; grid 32768, block 256
__global__ void convert_kernel(const float* __restrict__ x, unsigned short* __restrict__ xq) {
    const int blk = blockIdx.x;
    const int hh  = blk & 127;
    const int bg_ = blk >> 7;
    const int g   = bg_ & 31;
    const int b   = bg_ >> 5;
    __shared__ float sx[8][128];
    const int tid = threadIdx.x;
#pragma unroll
    for (int i = 0; i < 4; ++i) {
        const int idx = tid + i * 256;
        const int c8 = idx >> 7, p = idx & 127;
        sx[c8][p] = x[(((size_t)b * 256 + g * 8 + c8) * 128 + hh) * 128 + p];
    }
    __syncthreads();
    if (tid < 128) {
        const int p = tid;
        unsigned short u[8];
#pragma unroll
        for (int j = 0; j < 8; ++j) u[j] = f2bf(sx[j][p]);
        *(int4*)(xq + ((((size_t)b * 32 + g) * 128 + hh) * 128 + p) * 8) = pack8(u);
    }
}

// ---------------------------------------------------------------------------
// Modulated conv, implicit GEMM: M=256 (o), N=128 (one output row), K=2304.
// B staged ONCE per cc (3 raw rows, 24KB, tap = ds_read offset);
// A triple-buffered via global_load_lds with counted-vmcnt barriers (T4);
// setprio around MFMA cluster (T5). Input always bf16 NHWC8.
// Fused: +bias, leaky*sqrt2, PixelNorm; !FINAL_OUT writes NHWC8 bf16, else fp32 NCHW.
template<bool FINAL_OUT>
__global__ __launch_bounds__(256, 2) void conv_kernel(
    const unsigned short* __restrict__ in_q, const unsigned short* __restrict__ wmod,
    const float* __restrict__ bias, const unsigned short* __restrict__ zpg,
    void* __restrict__ out_v) {

    __shared__ __align__(16) char ldsA[49152];   // 3 x 16 KB weight slabs
    __shared__ __align__(16) char ldsB[24640];   // [3 rows][128 px][64B] + 64B zero slot
    __shared__ float sbias[256];

    const int tid  = threadIdx.x;
    const int bh   = (blockIdx.x & 7) * 128 + (blockIdx.x >> 3);  // XCD-contiguous
    const int b    = bh >> 7;
    const int h    = bh & 127;
    const int lane = tid & 63;
    const int wr   = tid >> 6;
    const int wm   = wr & 1;        // M half (128 o's)
    const int wn   = wr >> 1;       // N half (64 px)
    const int l31  = lane & 31;
    const int khg  = lane >> 5;     // k-octet group within frag

    sbias[tid] = bias[tid];
    if (tid < 4) *(int4*)(ldsB + 24576 + tid * 16) = (int4){0, 0, 0, 0};

    // A-frag LDS offsets (chunk XOR swizzle, matches fold's global pre-swizzle)
    int aoff[4][2];
#pragma unroll
    for (int mb = 0; mb < 4; ++mb)
#pragma unroll
        for (int kh = 0; kh < 2; ++kh) {
            const int o = wm * 128 + mb * 32 + l31;
            aoff[mb][kh] = o * 64 + (((khg + kh * 2) ^ ((o >> 1) & 3)) << 4);
        }

    // B-frag offsets for dx=0/1/2 at dy=0 (add dy*8192 at use; swizzle is
    // invariant under +128 rows since (128>>1)&3 == 0)
    int bC[2][2], bL[2][2], bR[2][2];
#pragma unroll
    for (int nb = 0; nb < 2; ++nb)
#pragma unroll
        for (int kh = 0; kh < 2; ++kh) {
            const int cx0 = wn * 64 + nb * 32 + l31;
            const int clog = khg + kh * 2;
            const int cl = cx0 - 1, cr = cx0 + 1;
            bC[nb][kh] = cx0 * 64 + ((clog ^ ((cx0 >> 1) & 3)) << 4);
            bL[nb][kh] = cl * 64 + ((clog ^ ((cl >> 1) & 3)) << 4);
            bR[nb][kh] = cr * 64 + ((clog ^ ((cr >> 1) & 3)) << 4);
        }
    const bool isL = (wn == 0) && (l31 == 0);    // cx0==0   (only nb==0)
    const bool isR = (wn == 1) && (l31 == 31);   // cx0==127 (only nb==1)

    const unsigned short* wmb = wmod + (size_t)b * 589824;
    const unsigned short* xqb = in_q + (size_t)b * 4194304;   // [32][128][128][8]

    auto issueA = [&](const char* src, int bufidx) {
        char* dstb = ldsA + bufidx * 16384 + wr * 1024;      // wave-uniform base
        const char* s = src + wr * 1024 + lane * 16;
#pragma unroll
        for (int i = 0; i < 4; ++i)
            gld_lds16(s + i * 4096, dstb + i * 4096);
    };

    auto issueB = [&](int ccn) {
#pragma unroll
        for (int i = 0; i < 6; ++i) {
            const int slot = i * 256 + tid;          // 0..1535
            const int rowidx = slot >> 2;            // 0..383 : r*128 + px
            const int cph = slot & 3;
            const int r = rowidx >> 7;               // 0..2  (dy row)
            const int pxs = rowidx & 127;
            const int clog = cph ^ ((rowidx >> 1) & 3);
            const int hin = h + r - 1;
            const unsigned short* src = ((unsigned)hin < 128u)
                ? xqb + (((size_t)(ccn * 4 + clog) * 128 + hin) * 128 + pxs) * 8
                : zpg;
            gld_lds16(src, ldsB + (i * 256 + wr * 64) * 16);  // wave-uniform base
        }
    };

    f32x16 acc[4][2];
#pragma unroll
    for (int mb = 0; mb < 4; ++mb)
#pragma unroll
        for (int nb = 0; nb < 2; ++nb)
#pragma unroll
            for (int r = 0; r < 16; ++r) acc[mb][nb][r] = 0.f;

    // prologue: B(cc0), A slabs 0,1 -> bufs 0,1
    issueB(0);
    issueA((const char*)wmb, 0);
    issueA((const char*)wmb + 16384, 1);
    __syncthreads();

    const char* gA = (const char*)wmb + 32768;
#pragma unroll 1
    for (int cc = 0; cc < 8; ++cc) {
#pragma unroll
        for (int t = 0; t < 9; ++t) {
            const int dy = t / 3, dx = t - (t / 3) * 3;
            const int cur = t % 3, tgt = (t + 2) % 3;   // cc*9 ≡ 0 mod 3
            const bool doIssue = (cc < 7) || (t < 7);
            if (doIssue) { issueA(gA, tgt); gA += 16384; }

            const char* Ac = ldsA + cur * 16384;
            short8 af[4][2], bf[2][2];
#pragma unroll
            for (int mb = 0; mb < 4; ++mb)
#pragma unroll
                for (int kh = 0; kh < 2; ++kh) af[mb][kh] = *(const short8*)(Ac + aoff[mb][kh]);
#pragma unroll
            for (int nb = 0; nb < 2; ++nb)
#pragma unroll
                for (int kh = 0; kh < 2; ++kh) {
                    int off;
                    if (dx == 1) {
                        off = bC[nb][kh] + dy * 8192;
                    } else if (dx == 0) {
                        off = bL[nb][kh] + dy * 8192;
                        if (nb == 0) off = isL ? 24576 : off;
                    } else {
                        off = bR[nb][kh] + dy * 8192;
                        if (nb == 1) off = isR ? 24576 : off;
                    }
                    bf[nb][kh] = *(const short8*)(ldsB + off);
                }

            __builtin_amdgcn_s_setprio(1);
#pragma unroll
            for (int kh = 0; kh < 2; ++kh)
#pragma unroll
                for (int mb = 0; mb < 4; ++mb)
#pragma unroll
                    for (int nb = 0; nb < 2; ++nb)
                        acc[mb][nb] = __builtin_amdgcn_mfma_f32_32x32x16_bf16(
                            af[mb][kh], bf[nb][kh], acc[mb][nb], 0, 0, 0);
            __builtin_amdgcn_s_setprio(0);

            // counted-vmcnt barrier: keep this step's 4 A-issues in flight
            if (doIssue) asm volatile("s_waitcnt vmcnt(4) lgkmcnt(0)" ::: "memory");
            else         asm volatile("s_waitcnt vmcnt(0) lgkmcnt(0)" ::: "memory");
            __builtin_amdgcn_sched_barrier(0);
            __builtin_amdgcn_s_barrier();
        }
        if (cc < 7) {
            issueB(cc + 1);     // single B buffer: all tap reads done (barrier above)
            __syncthreads();    // full drain before next cc reads B
        }
    }

    // ---------------- epilogue: bias + leaky*sqrt2 + PixelNorm ----------------
    float psum[2] = {0.f, 0.f};
    const float actGain = 1.4142135623730951f;
#pragma unroll
    for (int mb = 0; mb < 4; ++mb)
#pragma unroll
        for (int rg = 0; rg < 16; ++rg) {
            const int row = (rg & 3) + 8 * (rg >> 2) + 4 * khg;
            const float bo = sbias[wm * 128 + mb * 32 + row];
#pragma unroll
            for (int nb = 0; nb < 2; ++nb) {
                float v = acc[mb][nb][rg] + bo;
                v = (v > 0.f ? v : 0.2f * v) * actGain;
                acc[mb][nb][rg] = v;
                psum[nb] += v * v;
            }
        }
    psum[0] += __shfl_xor(psum[0], 32);
    psum[1] += __shfl_xor(psum[1], 32);
    float* red = (float*)ldsA;
    if (lane < 32) {
        red[(wn * 2 + wm) * 64 + l31]      = psum[0];
        red[(wn * 2 + wm) * 64 + 32 + l31] = psum[1];
    }
    __syncthreads();
    float rs[2];
#pragma unroll
    for (int nb = 0; nb < 2; ++nb) {
        const float ssum = red[(wn * 2) * 64 + nb * 32 + l31]
                         + red[(wn * 2 + 1) * 64 + nb * 32 + l31];
        rs[nb] = rsqrtf(ssum * (1.0f / 256.0f) + 1e-8f);
    }

    if (FINAL_OUT) {
        float* outF = (float*)out_v;
#pragma unroll
        for (int mb = 0; mb < 4; ++mb)
#pragma unroll
            for (int rg = 0; rg < 16; ++rg) {
                const int row = (rg & 3) + 8 * (rg >> 2) + 4 * khg;
                const int o = wm * 128 + mb * 32 + row;
                const size_t rb = (((size_t)b * 256 + o) * 128 + h) * 128;
#pragma unroll
                for (int nb = 0; nb < 2; ++nb)
                    outF[rb + wn * 64 + nb * 32 + l31] = acc[mb][nb][rg] * rs[nb];
            }
    } else {
        // transpose 128o x 64px (per wave) -> NHWC8 bf16 via per-wave LDS region.
        // FULLY UNROLLED (rule #20: runtime mb would force acc into scratch).
        unsigned short* outB = (unsigned short*)out_v;
        char* wreg = ldsA + wr * 4096;    // [64 px][32 o] bf16, chunk-swizzled
        __syncthreads();                  // red reads done before overwriting ldsA
#pragma unroll
        for (int mb = 0; mb < 4; ++mb) {
#pragma unroll
            for (int rg = 0; rg < 16; rg += 2) {
                const int row = (rg & 3) + 8 * (rg >> 2) + 4 * khg;   // even, 0..31
#pragma unroll
                for (int nb = 0; nb < 2; ++nb) {
                    const int pxl = nb * 32 + l31;
                    const unsigned lo = f2bf(acc[mb][nb][rg]     * rs[nb]);
                    const unsigned hi = f2bf(acc[mb][nb][rg + 1] * rs[nb]);
                    *(unsigned int*)(wreg + pxl * 64 + (((row >> 3) ^ (pxl & 3)) << 4)
                                     + (row & 7) * 2) = lo | (hi << 16);
                }
            }
            asm volatile("s_waitcnt lgkmcnt(0)" ::: "memory");
#pragma unroll
            for (int oc = 0; oc < 4; ++oc) {
                const int4 v = *(const int4*)(wreg + lane * 64 + ((oc ^ (lane & 3)) << 4));
                const int g = wm * 16 + mb * 4 + oc;
                *(int4*)(outB + ((((size_t)b * 32 + g) * 128 + h) * 128 + wn * 64 + lane) * 8) = v;
            }
            asm volatile("s_waitcnt lgkmcnt(0)" ::: "memory");
        }
    }
}

// ---------------------------------------------------------------------------
extern "C" void kernel_launch(void* const* d_in, const int* in_sizes, int n_in,
                              void* d_out, int out_size, void* d_ws, size_t ws_size,
                              hipStream_t stream) {
    (void)in_sizes; (void)n_in; (void)out_size; (void)ws_size;
    const float* x      = (const float*)d_in[0];
    const float* latent = (const float*)d_in[1];
    const float* w0     = (const float*)d_in[2];
    const float* b0     = (const float*)d_in[3];
    const float* el0w   = (const float*)d_in[4];
    const float* el0b   = (const float*)d_in[5];
    const float* w1     = (const float*)d_in[6];
    const float* b1     = (const float*)d_in[7];
    const float* el1w   = (const float*)d_in[8];
    const float* el1b   = (const float*)d_in[9];

    char* ws = (char*)d_ws;
    float* s_arr = (float*)ws;                                   // 16 KB
    float* d_arr = (float*)(ws + 16384);                         // 16 KB
    float* wsq   = (float*)(ws + 32768);                         // 512 KB (reused as zero page)
    unsigned short* zpg = (unsigned short*)(ws + 32768);         // 256 B zeros (after demod)
    unsigned short* wm0 = (unsigned short*)(ws + 557056);        // 9.4 MB
    unsigned short* wm1 = (unsigned short*)(ws + 9994240);       // 9.4 MB
    unsigned short* xq  = (unsigned short*)(ws + 19431424);      // 67 MB
    unsigned short* tmp = (unsigned short*)(ws + 86540288);      // 67 MB

    style_kernel<<<16, 256, 0, stream>>>(latent, el0w, el0b, el1w, el1b, s_arr);
    wsq_kernel<<<512, 256, 0, stream>>>(w0, w1, wsq);
    demod_kernel<<<16, 256, 0, stream>>>(s_arr, wsq, d_arr);
    hipMemsetAsync(zpg, 0, 256, stream);   // wsq no longer needed; reuse as zero page
    fold_kernel<<<dim3(18432, 2), 256, 0, stream>>>(w0, w1, s_arr, d_arr, wm0, wm1);
    convert_kernel<<<32768, 256, 0, stream>>>(x, xq);

    conv_kernel<false><<<1024, 256, 0, stream>>>(xq, wm0, b0, zpg, tmp);
    conv_kernel<true><<<1024, 256, 0, stream>>>(tmp, wm1, b1, zpg, d_out);
}

// Round 5
// 367.274 us; speedup vs baseline: 4.8231x; 1.0850x over previous
//
#include <hip/hip_runtime.h>
#include <hip/hip_bf16.h>

typedef __attribute__((ext_vector_type(8))) short short8;
typedef __attribute__((ext_vector_type(16))) float f32x16;

typedef const __attribute__((address_space(1))) unsigned int* gas1_t;
typedef __attribute__((address_space(3))) unsigned int* las3_t;

__device__ __forceinline__ unsigned short f2bf(float x) {
    unsigned int u = __float_as_uint(x);
    u = (u + 0x7fffu + ((u >> 16) & 1u)) >> 16;   // RNE
    return (unsigned short)u;
}

__device__ __forceinline__ int4 pack8(const unsigned short* u) {
    int4 p;
    p.x = (int)((unsigned)u[0] | ((unsigned)u[1] << 16));
    p.y = (int)((unsigned)u[2] | ((unsigned)u[3] << 16));
    p.z = (int)((unsigned)u[4] | ((unsigned)u[5] << 16));
    p.w = (int)((unsigned)u[6] | ((unsigned)u[7] << 16));
    return p;
}

__device__ __forceinline__ void gld_lds16(const void* g, void* l) {
    __builtin_amdgcn_global_load_lds((gas1_t)g, (las3_t)l, 16, 0, 0);
}

// ---------------------------------------------------------------------------
// s[cv][b][c] = 1 + PixelNorm(EqualLinear(latent)); grid 16, block 256
__global__ void style_kernel(const float* __restrict__ latent,
                             const float* __restrict__ elw0, const float* __restrict__ elb0,
                             const float* __restrict__ elw1, const float* __restrict__ elb1,
                             float* __restrict__ s_arr) {
    const int cv = blockIdx.x >> 3;
    const int b  = blockIdx.x & 7;
    const int c  = threadIdx.x;
    const float* elw = cv ? elw1 : elw0;
    const float* elb = cv ? elb1 : elb0;

    __shared__ float lat[512];
    lat[c] = latent[b * 512 + c];
    lat[c + 256] = latent[b * 512 + c + 256];
    __syncthreads();

    float accv = 0.f;
    const float* wrow = elw + (size_t)c * 512;
#pragma unroll 8
    for (int k = 0; k < 512; ++k) accv += lat[k] * wrow[k];
    const float lin = accv * 0.04419417382415922f + elb[c];

    float sq = lin * lin;
#pragma unroll
    for (int off = 32; off >= 1; off >>= 1) sq += __shfl_xor(sq, off);
    __shared__ float wsum[4];
    if ((threadIdx.x & 63) == 0) wsum[threadIdx.x >> 6] = sq;
    __syncthreads();
    const float total = wsum[0] + wsum[1] + wsum[2] + wsum[3];
    const float s = 1.0f + lin * rsqrtf(total * (1.0f / 256.0f) + 1e-8f);
    s_arr[(cv * 8 + b) * 256 + c] = s;
}

// wsq[cv][o][c] = sum_t (w*sc)^2 ; grid 512, block 256
__global__ void wsq_kernel(const float* __restrict__ w0, const float* __restrict__ w1,
                           float* __restrict__ wsq) {
    const int cv = blockIdx.x >> 8;
    const int o  = blockIdx.x & 255;
    const int c  = threadIdx.x;
    const float* w = cv ? w1 : w0;
    const size_t base = ((size_t)o * 256 + c) * 9;
    float ssum = 0.f;
#pragma unroll
    for (int t = 0; t < 9; ++t) { float v = w[base + t]; ssum += v * v; }
    wsq[((size_t)cv * 256 + o) * 256 + c] = ssum * (2.0f / 2304.0f);
}

// d[cv][b][o] = rsqrt(sum_c s^2 * wsq + 1e-5) ; grid 16, block 256
__global__ void demod_kernel(const float* __restrict__ s_arr, const float* __restrict__ wsq,
                             float* __restrict__ d_arr) {
    const int cv = blockIdx.x >> 3;
    const int b  = blockIdx.x & 7;
    const int o  = threadIdx.x;
    __shared__ float ss[256];
    float sv = s_arr[(cv * 8 + b) * 256 + o];
    ss[o] = sv * sv;
    __syncthreads();
    const float* wrow = wsq + ((size_t)cv * 256 + o) * 256;
    float accv = 0.f;
#pragma unroll 8
    for (int c = 0; c < 256; ++c) accv += ss[c] * wrow[c];
    d_arr[(cv * 8 + b) * 256 + o] = rsqrtf(accv + 1e-5f);
}

// wmod[b][cc][t] slab (8192 elems) laid out [k-octet 0..3][o 0..255][8 ch]
// -> conflict-free lane-contiguous ds_read_b128 frags. grid (18432,2), block 256
__global__ void fold_kernel(const float* __restrict__ w0, const float* __restrict__ w1,
                            const float* __restrict__ s_arr, const float* __restrict__ d_arr,
                            unsigned short* __restrict__ wm0, unsigned short* __restrict__ wm1) {
    const int cv = blockIdx.y;
    const int e  = blockIdx.x * 256 + threadIdx.x;       // 0 .. 4718591
    const float* w = cv ? w1 : w0;
    unsigned short* wm = cv ? wm1 : wm0;
    const int slab = e >> 13;            // 0..575  = ((b*8)+cc)*9 + t
    const int idx  = e & 8191;
    const int b  = slab / 72;
    const int s2 = slab - b * 72;
    const int cc = s2 / 9;
    const int t  = s2 - cc * 9;
    const int o  = idx >> 5;
    const int c5 = idx & 31;
    const int c  = cc * 32 + c5;
    const float val = w[((size_t)o * 256 + c) * 9 + t] * 0.029462782549439483f  // sqrt(2/2304)
                    * s_arr[(cv * 8 + b) * 256 + c] * d_arr[(cv * 8 + b) * 256 + o];
    wm[((size_t)slab << 13) + (c5 >> 3) * 2048 + o * 8 + (c5 & 7)] = f2bf(val);
}

// x (fp32 NCHW) -> xq (bf16 NHWC8): [b][g=32][h][w][8ch]; grid 32768, block 256
__global__ void convert_kernel(const float* __restrict__ x, unsigned short* __restrict__ xq) {
    const int blk = blockIdx.x;
    const int hh  = blk & 127;
    const int bg_ = blk >> 7;
    const int g   = bg_ & 31;
    const int b   = bg_ >> 5;
    __shared__ float sx[8][128];
    const int tid = threadIdx.x;
#pragma unroll
    for (int i = 0; i < 4; ++i) {
        const int idx = tid + i * 256;
        const int c8 = idx >> 7, p = idx & 127;
        sx[c8][p] = x[(((size_t)b * 256 + g * 8 + c8) * 128 + hh) * 128 + p];
    }
    __syncthreads();
    if (tid < 128) {
        const int p = tid;
        unsigned short u[8];
#pragma unroll
        for (int j = 0; j < 8; ++j) u[j] = f2bf(sx[j][p]);
        *(int4*)(xq + ((((size_t)b * 32 + g) * 128 + hh) * 128 + p) * 8) = pack8(u);
    }
}

// ---------------------------------------------------------------------------
// Modulated conv, implicit GEMM: M=256 (o), N=256 (2 rows x 128 px), K=2304.
// 8 waves (512 thr), wave tile 64o x 128px; A [koct][o] triple-buffered via
// global_load_lds + counted vmcnt; B [row][koct][px] staged once per cc
// (4 rows, taps = ds_read offsets). All LDS frag reads lane-contiguous.
// Fused: +bias, leaky*sqrt2, PixelNorm; !FINAL_OUT -> NHWC8 bf16, else fp32 NCHW.
template<bool FINAL_OUT>
__global__ __launch_bounds__(512, 2) void conv_kernel(
    const unsigned short* __restrict__ in_q, const unsigned short* __restrict__ wmod,
    const float* __restrict__ bias, const unsigned short* __restrict__ zpg,
    void* __restrict__ out_v) {

    // [0,49152) A: 3 slabs x 16KB   [49152,81920) B: 4 rows x 8KB
    // [81920,81984) zero slot       [81984,83008) bias   [83008,87104) red
    __shared__ __align__(16) char lds[87104];

    const int tid  = threadIdx.x;
    const int b    = blockIdx.x & 7;          // XCD-affine (same b -> same XCD)
    const int rp   = blockIdx.x >> 3;         // 0..63 row pair
    const int h0   = rp * 2;
    const int lane = tid & 63;
    const int wr   = tid >> 6;                // 0..7
    const int wm   = wr & 3;                  // o-quarter (64 o's)
    const int wn   = wr >> 2;                 // row within pair
    const int l31  = lane & 31;
    const int khg  = lane >> 5;               // k-octet half

    float* sbias = (float*)(lds + 81984);
    if (tid < 256) sbias[tid] = bias[tid];
    if (tid < 4)   *(int4*)(lds + 81920 + tid * 16) = (int4){0, 0, 0, 0};

    // A frag byte offsets within a slab: [koct][o][16B]
    int aoff[2][2];
#pragma unroll
    for (int mb = 0; mb < 2; ++mb)
#pragma unroll
        for (int kh = 0; kh < 2; ++kh)
            aoff[mb][kh] = ((khg + 2 * kh) * 256 + wm * 64 + mb * 32 + l31) * 16;

    const unsigned short* wmb = wmod + (size_t)b * 589824;
    const unsigned short* xqb = in_q + (size_t)b * 4194304;   // [32][128][128][8]

    auto issueA = [&](const char* src, int buf) {
        char* db = lds + buf * 16384 + wr * 2048;            // wave-uniform base
        const char* s = src + wr * 2048 + lane * 16;
        gld_lds16(s,        db);
        gld_lds16(s + 1024, db + 1024);
    };

    auto issueB = [&](int cc) {
        const int chunk = tid >> 7, px = tid & 127;          // slot within a row
#pragma unroll
        for (int r = 0; r < 4; ++r) {
            const int hin = h0 - 1 + r;
            const unsigned short* src = ((unsigned)hin < 128u)
                ? xqb + (((size_t)(cc * 4 + chunk) * 128 + hin) * 128 + px) * 8
                : zpg;
            gld_lds16(src, lds + 49152 + r * 8192 + wr * 1024);  // uniform base
        }
    };

    f32x16 acc[2][4];
#pragma unroll
    for (int mb = 0; mb < 2; ++mb)
#pragma unroll
        for (int nb = 0; nb < 4; ++nb)
#pragma unroll
            for (int r = 0; r < 16; ++r) acc[mb][nb][r] = 0.f;

    // prologue: B(cc0), A slabs 0,1 -> bufs 0,1
    issueB(0);
    issueA((const char*)wmb, 0);
    issueA((const char*)wmb + 16384, 1);
    __syncthreads();

    const char* gA = (const char*)wmb + 32768;
#pragma unroll 1
    for (int cc = 0; cc < 8; ++cc) {
#pragma unroll
        for (int t = 0; t < 9; ++t) {
            const int dy = t / 3, dx = t - (t / 3) * 3;
            const int cur = t % 3, tgt = (t + 2) % 3;        // cc*9 ≡ 0 mod 3
            const bool doIssue = (t <= 6) || (cc < 7);
            if (doIssue) { issueA(gA, tgt); gA += 16384; }

            const char* Ac = lds + cur * 16384;
            short8 af[2][2], bf[4][2];
#pragma unroll
            for (int mb = 0; mb < 2; ++mb)
#pragma unroll
                for (int kh = 0; kh < 2; ++kh)
                    af[mb][kh] = *(const short8*)(Ac + aoff[mb][kh]);
#pragma unroll
            for (int nb = 0; nb < 4; ++nb)
#pragma unroll
                for (int kh = 0; kh < 2; ++kh) {
                    int off = 49152 + (wn + dy) * 8192 + (khg + 2 * kh) * 2048
                            + (nb * 32 + l31 + dx - 1) * 16;
                    if (dx == 0 && nb == 0) off = (l31 == 0)  ? 81920 : off;
                    if (dx == 2 && nb == 3) off = (l31 == 31) ? 81920 : off;
                    bf[nb][kh] = *(const short8*)(lds + off);
                }

            __builtin_amdgcn_s_setprio(1);
#pragma unroll
            for (int kh = 0; kh < 2; ++kh)
#pragma unroll
                for (int mb = 0; mb < 2; ++mb)
#pragma unroll
                    for (int nb = 0; nb < 4; ++nb)
                        acc[mb][nb] = __builtin_amdgcn_mfma_f32_32x32x16_bf16(
                            af[mb][kh], bf[nb][kh], acc[mb][nb], 0, 0, 0);
            __builtin_amdgcn_s_setprio(0);

            if (doIssue) asm volatile("s_waitcnt vmcnt(2) lgkmcnt(0)" ::: "memory");
            else         asm volatile("s_waitcnt vmcnt(0) lgkmcnt(0)" ::: "memory");
            __builtin_amdgcn_sched_barrier(0);
            __builtin_amdgcn_s_barrier();
        }
        if (cc < 7) {
            issueB(cc + 1);   // B single-buffered: all tap reads done (barrier above)
            asm volatile("s_waitcnt vmcnt(0)" ::: "memory");
            __builtin_amdgcn_sched_barrier(0);
            __builtin_amdgcn_s_barrier();
        }
    }

    // ---------------- epilogue: bias + leaky*sqrt2 + PixelNorm ----------------
    float psum[4] = {0.f, 0.f, 0.f, 0.f};
    const float actGain = 1.4142135623730951f;
#pragma unroll
    for (int mb = 0; mb < 2; ++mb)
#pragma unroll
        for (int rg = 0; rg < 16; ++rg) {
            const int row = (rg & 3) + 8 * (rg >> 2) + 4 * khg;
            const float bo = sbias[wm * 64 + mb * 32 + row];
#pragma unroll
            for (int nb = 0; nb < 4; ++nb) {
                float v = acc[mb][nb][rg] + bo;
                v = (v > 0.f ? v : 0.2f * v) * actGain;
                acc[mb][nb][rg] = v;
                psum[nb] += v * v;
            }
        }
#pragma unroll
    for (int nb = 0; nb < 4; ++nb) psum[nb] += __shfl_xor(psum[nb], 32);
    float* red = (float*)(lds + 83008);       // [wn][wm][128 px]
    if (lane < 32) {
#pragma unroll
        for (int nb = 0; nb < 4; ++nb)
            red[(wn * 4 + wm) * 128 + nb * 32 + l31] = psum[nb];
    }
    __syncthreads();
    float rs[4];
#pragma unroll
    for (int nb = 0; nb < 4; ++nb) {
        const int p = nb * 32 + l31;
        const float ssum = red[(wn * 4 + 0) * 128 + p] + red[(wn * 4 + 1) * 128 + p]
                         + red[(wn * 4 + 2) * 128 + p] + red[(wn * 4 + 3) * 128 + p];
        rs[nb] = rsqrtf(ssum * (1.0f / 256.0f) + 1e-8f);
    }

    const int h = h0 + wn;
    if (FINAL_OUT) {
        float* outF = (float*)out_v;
#pragma unroll
        for (int mb = 0; mb < 2; ++mb)
#pragma unroll
            for (int rg = 0; rg < 16; ++rg) {
                const int row = (rg & 3) + 8 * (rg >> 2) + 4 * khg;
                const int o = wm * 64 + mb * 32 + row;
                const size_t rb = (((size_t)b * 256 + o) * 128 + h) * 128;
#pragma unroll
                for (int nb = 0; nb < 4; ++nb)
                    outF[rb + nb * 32 + l31] = acc[mb][nb][rg] * rs[nb];
            }
    } else {
        // per-wave transpose 32o x 128px -> NHWC8 bf16, fully unrolled (rule #20)
        unsigned short* outB = (unsigned short*)out_v;
        char* wreg = lds + wr * 8192;         // [128 px][32 o] bf16, chunk-swizzled
#pragma unroll
        for (int mb = 0; mb < 2; ++mb) {
#pragma unroll
            for (int rg = 0; rg < 16; rg += 2) {
                const int row = (rg & 3) + 8 * (rg >> 2) + 4 * khg;   // even, 0..31
#pragma unroll
                for (int nb = 0; nb < 4; ++nb) {
                    const int pxl = nb * 32 + l31;
                    const unsigned lo = f2bf(acc[mb][nb][rg]     * rs[nb]);
                    const unsigned hi = f2bf(acc[mb][nb][rg + 1] * rs[nb]);
                    *(unsigned int*)(wreg + pxl * 64 + (((row >> 3) ^ (pxl & 3)) << 4)
                                     + (row & 7) * 2) = lo | (hi << 16);
                }
            }
            asm volatile("s_waitcnt lgkmcnt(0)" ::: "memory");
#pragma unroll
            for (int oc = 0; oc < 4; ++oc)
#pragma unroll
                for (int ph = 0; ph < 2; ++ph) {
                    const int pxl = ph * 64 + lane;
                    const int4 v = *(const int4*)(wreg + pxl * 64 + ((oc ^ (pxl & 3)) << 4));
                    const int g = wm * 8 + mb * 4 + oc;
                    *(int4*)(outB + ((((size_t)b * 32 + g) * 128 + h) * 128 + pxl) * 8) = v;
                }
            asm volatile("s_waitcnt lgkmcnt(0)" ::: "memory");
        }
    }
}

// ---------------------------------------------------------------------------
extern "C" void kernel_launch(void* const* d_in, const int* in_sizes, int n_in,
                              void* d_out, int out_size, void* d_ws, size_t ws_size,
                              hipStream_t stream) {
    (void)in_sizes; (void)n_in; (void)out_size; (void)ws_size;
    const float* x      = (const float*)d_in[0];
    const float* latent = (const float*)d_in[1];
    const float* w0     = (const float*)d_in[2];
    const float* b0     = (const float*)d_in[3];
    const float* el0w   = (const float*)d_in[4];
    const float* el0b   = (const float*)d_in[5];
    const float* w1     = (const float*)d_in[6];
    const float* b1     = (const float*)d_in[7];
    const float* el1w   = (const float*)d_in[8];
    const float* el1b   = (const float*)d_in[9];

    char* ws = (char*)d_ws;
    float* s_arr = (float*)ws;                                   // 16 KB
    float* d_arr = (float*)(ws + 16384);                         // 16 KB
    float* wsq   = (float*)(ws + 32768);                         // 512 KB (reused as zero page)
    unsigned short* zpg = (unsigned short*)(ws + 32768);         // 256 B zeros (after demod)
    unsigned short* wm0 = (unsigned short*)(ws + 557056);        // 9.4 MB
    unsigned short* wm1 = (unsigned short*)(ws + 9994240);       // 9.4 MB
    unsigned short* xq  = (unsigned short*)(ws + 19431424);      // 67 MB
    unsigned short* tmp = (unsigned short*)(ws + 86540288);      // 67 MB

    style_kernel<<<16, 256, 0, stream>>>(latent, el0w, el0b, el1w, el1b, s_arr);
    wsq_kernel<<<512, 256, 0, stream>>>(w0, w1, wsq);
    demod_kernel<<<16, 256, 0, stream>>>(s_arr, wsq, d_arr);
    hipMemsetAsync(zpg, 0, 256, stream);   // wsq no longer needed; reuse as zero page
    fold_kernel<<<dim3(18432, 2), 256, 0, stream>>>(w0, w1, s_arr, d_arr, wm0, wm1);
    convert_kernel<<<32768, 256, 0, stream>>>(x, xq);

    conv_kernel<false><<<512, 512, 0, stream>>>(xq, wm0, b0, zpg, tmp);
    conv_kernel<true><<<512, 512, 0, stream>>>(tmp, wm1, b1, zpg, d_out);
}